// Round 5
// baseline (40535.852 us; speedup 1.0000x reference)
//
#include <hip/hip_runtime.h>
#include <cstdint>

// ===================== variant switches (flip across rounds if absmax fails) =====================
// U1/U2: jax_threefry_partitionable (default True in modern jax). 0 = original half-split layout.
#define PRNG_PARTITIONABLE 1
// U3: 0 = sigmoid as 1/(1+exp(-x)) (current XLA LogisticExpander); 1 = 0.5+0.5*tanh(0.5x) (old XLA)
#define SIGMOID_TANH_FORM 0
// U4: 0 = exp polynomial with separate mul/add (no fast-math); 1 = fused fmaf
#define EXP_POLY_FMA 0

constexpr int LATENT = 128;
constexpr int NS = 524288;
constexpr int HALF_ROWS = NS / 2;         // 262144 ; wave owns rows (r, r+HALF_ROWS)
constexpr uint32_t HALF_CNT = 1u << 25;   // flat-count offset between paired rows (HALF_ROWS*128)
constexpr int STEPS = 30;
constexpr int TPB = 512;                  // 8 waves/block
constexpr int WAVES_PB = TPB / 64;
constexpr int NBLOCKS = HALF_ROWS / WAVES_PB;  // 32768

// ---------------- threefry2x32, 20 rounds, exactly jax's schedule ----------------
__host__ __device__ __forceinline__ void tf2x32(uint32_t k0, uint32_t k1,
                                                uint32_t x0, uint32_t x1,
                                                uint32_t& o0, uint32_t& o1) {
  const uint32_t ks2 = k0 ^ k1 ^ 0x1BD11BDAu;
  x0 += k0; x1 += k1;
#define TFR(r) { x0 += x1; x1 = (x1 << (r)) | (x1 >> (32 - (r))); x1 ^= x0; }
  TFR(13) TFR(15) TFR(26) TFR(6)
  x0 += k1;  x1 += ks2 + 1u;
  TFR(17) TFR(29) TFR(16) TFR(24)
  x0 += ks2; x1 += k0 + 2u;
  TFR(13) TFR(15) TFR(26) TFR(6)
  x0 += k0;  x1 += k1 + 3u;
  TFR(17) TFR(29) TFR(16) TFR(24)
  x0 += k1;  x1 += ks2 + 4u;
  TFR(13) TFR(15) TFR(26) TFR(6)
  x0 += ks2; x1 += k0 + 5u;
#undef TFR
  o0 = x0; o1 = x1;
}

// random_bits(key, 32, (NS,128)) element for paired rows: c = r0*128 + j (r0 < HALF_ROWS).
// partitionable: bits[f] = o0^o1 of block(key, hi=0, lo=f)   -> two blocks, rows r0 and r0+HALF_ROWS
// original:      bits[f<2^25] = block(key, f, f+2^25).o0 ; bits[f>=2^25] = .o1  -> one shared block
__device__ __forceinline__ void rand_bits_pair(uint32_t ka, uint32_t kb, uint32_t c,
                                               uint32_t& bits_r0, uint32_t& bits_r1) {
#if PRNG_PARTITIONABLE
  uint32_t a, b;
  tf2x32(ka, kb, 0u, c, a, b);            bits_r0 = a ^ b;
  tf2x32(ka, kb, 0u, c + HALF_CNT, a, b); bits_r1 = a ^ b;
#else
  uint32_t a, b;
  tf2x32(ka, kb, c, c + HALF_CNT, a, b);  bits_r0 = a; bits_r1 = b;
#endif
}

// jax uniform f32: bitcast((bits>>9)|0x3f800000) - 1.0  (exact; *1.0+0.0 and max(0,.) are no-ops)
__device__ __forceinline__ float bits_to_u(uint32_t b) {
  return __fsub_rn(__uint_as_float((b >> 9) | 0x3f800000u), 1.0f);
}

// XLA:CPU sigmoid. |logit| <= sum|W col| ~ 0.11 << 0.3466, so cephes exp has fx==0 identically:
// range reduction is exact identity and 2^fx scale is *1.0. All ops _rn to forbid contraction.
__device__ __forceinline__ float ref_sigmoid(float v) {
#if SIGMOID_TANH_FORM
  float t  = __fmul_rn(0.5f, v);
  float ax = fabsf(t);
  float x2 = __fmul_rn(t, t);
  float n = -2.76076847742355e-16f;
  n = __fadd_rn(__fmul_rn(x2, n),  2.00018790482477e-13f);
  n = __fadd_rn(__fmul_rn(x2, n), -8.60467152213735e-11f);
  n = __fadd_rn(__fmul_rn(x2, n),  5.12229709037114e-08f);
  n = __fadd_rn(__fmul_rn(x2, n),  1.48572235717979e-05f);
  n = __fadd_rn(__fmul_rn(x2, n),  6.37261928875436e-04f);
  n = __fadd_rn(__fmul_rn(x2, n),  4.89352455891786e-03f);
  n = __fmul_rn(t, n);
  float d = 1.19825839466702e-06f;
  d = __fadd_rn(__fmul_rn(x2, d), 1.18534705686654e-04f);
  d = __fadd_rn(__fmul_rn(x2, d), 2.26843463243900e-03f);
  d = __fadd_rn(__fmul_rn(x2, d), 4.89352518554385e-03f);
  float th = (ax < 0.0004f) ? t : __fdiv_rn(n, d);
  return __fadd_rn(0.5f, __fmul_rn(0.5f, th));
#else
  float a = -v;   // negate exact
#if EXP_POLY_FMA
  float y = __fmaf_rn(a, 1.9875691500E-4f, 1.3981999507E-3f);
  y = __fmaf_rn(y, a, 8.3334519073E-3f);
  y = __fmaf_rn(y, a, 4.1665795894E-2f);
  y = __fmaf_rn(y, a, 1.6666665459E-1f);
  y = __fmaf_rn(y, a, 5.0000001201E-1f);
  float a2 = __fmul_rn(a, a);
  y = __fmaf_rn(y, a2, a);
#else
  float y = __fadd_rn(__fmul_rn(a, 1.9875691500E-4f), 1.3981999507E-3f);
  y = __fadd_rn(__fmul_rn(y, a), 8.3334519073E-3f);
  y = __fadd_rn(__fmul_rn(y, a), 4.1665795894E-2f);
  y = __fadd_rn(__fmul_rn(y, a), 1.6666665459E-1f);
  y = __fadd_rn(__fmul_rn(y, a), 5.0000001201E-1f);
  float a2 = __fmul_rn(a, a);
  y = __fadd_rn(__fmul_rn(y, a2), a);
#endif
  float e = __fadd_rn(1.0f, y);                 // exp(-v), fx==0 path
  return __fdiv_rn(1.0f, __fadd_rn(1.0f, e));   // 1/(1+exp(-v))
#endif
}

struct KeyArgs {
  // sk[0..59]: step_keys[t] = (sk[2t], sk[2t+1]); sk[60..61]: randint lower-bits key k2
  uint32_t sk[62];
};

__global__ __launch_bounds__(TPB, 4)
void rbm_gibbs_kernel(const float* __restrict__ h, const float* __restrict__ W,
                      float* __restrict__ out, KeyArgs ka) {
  __shared__ float Ws[LATENT * LATENT];   // 64 KiB, row-major W[k][j]

  const int tid = threadIdx.x;
  {
    const float4* Wg = reinterpret_cast<const float4*>(W);
    float4* Ws4 = reinterpret_cast<float4*>(Ws);
    #pragma unroll
    for (int i = tid; i < LATENT * LATENT / 4; i += TPB) Ws4[i] = Wg[i];
  }
  __syncthreads();

  const int lane = tid & 63;
  const int wid  = blockIdx.x * WAVES_PB + (tid >> 6);   // [0, HALF_ROWS)
  const uint32_t cb = (uint32_t)wid * 128u;              // flat count base, < 2^25
  const int j0 = 2 * lane, j1 = 2 * lane + 1;            // this lane's two columns
  const float h0 = h[j0], h1 = h[j1];

  // ---- z0 = randint(k_init,...,0,2) = lower_bits & 1 ; masks: bit l <-> column 2l (even) / 2l+1 (odd)
  unsigned long long mE0, mO0, mE1, mO1;
  {
    uint32_t a0, a1, b0, b1;
    rand_bits_pair(ka.sk[60], ka.sk[61], cb + (uint32_t)j0, a0, a1);
    rand_bits_pair(ka.sk[60], ka.sk[61], cb + (uint32_t)j1, b0, b1);
    mE0 = __ballot((int)(a0 & 1u));
    mO0 = __ballot((int)(b0 & 1u));
    mE1 = __ballot((int)(a1 & 1u));
    mO1 = __ballot((int)(b1 & 1u));
  }

  const float2* Wp = reinterpret_cast<const float2*>(Ws);

  for (int t = 0; t < STEPS; ++t) {
    // ---- dot: strict k-ascending FMA chain from 0 (matches Eigen gebp per-element order)
    float a00 = 0.f, a01 = 0.f, a10 = 0.f, a11 = 0.f;
    #pragma unroll
    for (int m = 0; m < 64; ++m) {
      const float2 wa = Wp[m * 128 + lane];        // k=2m,   cols (2l,2l+1)
      const float2 wb = Wp[m * 128 + 64 + lane];   // k=2m+1, cols (2l,2l+1)
      const float fE0 = ((mE0 >> m) & 1ull) ? 1.0f : 0.0f;  // wave-uniform z bits
      const float fO0 = ((mO0 >> m) & 1ull) ? 1.0f : 0.0f;
      const float fE1 = ((mE1 >> m) & 1ull) ? 1.0f : 0.0f;
      const float fO1 = ((mO1 >> m) & 1ull) ? 1.0f : 0.0f;
      a00 = __fmaf_rn(fE0, wa.x, a00); a01 = __fmaf_rn(fE0, wa.y, a01);
      a00 = __fmaf_rn(fO0, wb.x, a00); a01 = __fmaf_rn(fO0, wb.y, a01);
      a10 = __fmaf_rn(fE1, wa.x, a10); a11 = __fmaf_rn(fE1, wa.y, a11);
      a10 = __fmaf_rn(fO1, wb.x, a10); a11 = __fmaf_rn(fO1, wb.y, a11);
    }

    // ---- uniforms for this step (step key via kernarg scalar loads)
    const uint32_t sa = ka.sk[2 * t], sb = ka.sk[2 * t + 1];
    uint32_t uA0, uA1, uB0, uB1;
    rand_bits_pair(sa, sb, cb + (uint32_t)j0, uA0, uA1);
    rand_bits_pair(sa, sb, cb + (uint32_t)j1, uB0, uB1);

    // ---- probs = sigmoid(h + dot) ; z_new = (u < probs)
    const float p00 = ref_sigmoid(__fadd_rn(h0, a00));
    const float p01 = ref_sigmoid(__fadd_rn(h1, a01));
    const float p10 = ref_sigmoid(__fadd_rn(h0, a10));
    const float p11 = ref_sigmoid(__fadd_rn(h1, a11));

    mE0 = __ballot((int)(bits_to_u(uA0) < p00));
    mO0 = __ballot((int)(bits_to_u(uB0) < p01));
    mE1 = __ballot((int)(bits_to_u(uA1) < p10));
    mO1 = __ballot((int)(bits_to_u(uB1) < p11));
  }

  // ---- write z_final rows wid and wid+HALF_ROWS (float2 per lane, coalesced)
  float2 z0o, z1o;
  z0o.x = (float)((mE0 >> lane) & 1ull);
  z0o.y = (float)((mO0 >> lane) & 1ull);
  z1o.x = (float)((mE1 >> lane) & 1ull);
  z1o.y = (float)((mO1 >> lane) & 1ull);
  float2* out2 = reinterpret_cast<float2*>(out);
  out2[(size_t)wid * 64 + lane] = z0o;
  out2[((size_t)wid + HALF_ROWS) * 64 + lane] = z1o;
}

extern "C" void kernel_launch(void* const* d_in, const int* in_sizes, int n_in,
                              void* d_out, int out_size, void* d_ws, size_t ws_size,
                              hipStream_t stream) {
  const float* h = (const float*)d_in[0];
  const float* W = (const float*)d_in[1];
  float* out = (float*)d_out;

  // ---- host-side key derivation, key = threefry_seed(42) = (0, 42)
  KeyArgs ka;
  const uint32_t K0 = 0u, K1 = 42u;
#if PRNG_PARTITIONABLE
  // fold-like split: split(key)[i] = block(key, 0, i)
  uint32_t ia, ib, la, lb;
  tf2x32(K0, K1, 0u, 0u, ia, ib);   // k_init
  tf2x32(K0, K1, 0u, 1u, la, lb);   // k_loop
  tf2x32(ia, ib, 0u, 1u, ka.sk[60], ka.sk[61]);   // k2 = split(k_init)[1] (randint lower bits)
  for (uint32_t t = 0; t < STEPS; ++t)
    tf2x32(la, lb, 0u, t, ka.sk[2 * t], ka.sk[2 * t + 1]);
#else
  // original split: counts iota(2*num) halved -> blocks (i, i+num); out = concat(o0s, o1s)
  uint32_t A0, A1, B0, B1;
  tf2x32(K0, K1, 0u, 2u, A0, A1);
  tf2x32(K0, K1, 1u, 3u, B0, B1);
  const uint32_t ini0 = A0, ini1 = B0, lp0 = A1, lp1 = B1;  // k_init, k_loop
  tf2x32(ini0, ini1, 0u, 2u, A0, A1);
  tf2x32(ini0, ini1, 1u, 3u, B0, B1);
  ka.sk[60] = A1; ka.sk[61] = B1;                            // k2 = split(k_init)[1]
  uint32_t flat[60];
  for (uint32_t i = 0; i < 30; ++i) {
    uint32_t o0, o1;
    tf2x32(lp0, lp1, i, i + 30u, o0, o1);
    flat[i] = o0; flat[30 + i] = o1;
  }
  for (int t = 0; t < STEPS; ++t) { ka.sk[2 * t] = flat[2 * t]; ka.sk[2 * t + 1] = flat[2 * t + 1]; }
#endif

  rbm_gibbs_kernel<<<NBLOCKS, TPB, 0, stream>>>(h, W, out, ka);
}

// Round 6
// 15139.505 us; speedup vs baseline: 2.6775x; 2.6775x over previous
//
#include <hip/hip_runtime.h>
#include <cstdint>

// Verified bit-exact in round 5 (absmax 0.0): partitionable threefry split
// (block(key,0,i)), randint(0,2)=lower_bits&1, uniform=(bits>>9)|0x3f800000 - 1,
// dot = strict k-ascending __fmaf_rn chain from 0, sigmoid = 1/(1+exp(-x)) with
// cephes exp separate mul/add on the fx==0 path. DO NOT change any arithmetic.

constexpr int LATENT = 128;
constexpr int NS = 524288;
constexpr int STEPS = 30;
constexpr int R = 4;                       // rows per wave (amortizes LDS reads)
constexpr int TPB = 512;                   // 8 waves/block
constexpr int WAVES_PB = TPB / 64;
constexpr int NWAVES = NS / R;             // 131072
constexpr int NBLOCKS = NWAVES / WAVES_PB; // 16384

// ---------------- threefry2x32, 20 rounds, exactly jax's schedule ----------------
struct TFOut { uint32_t a, b; };

__host__ __device__ constexpr TFOut tf2x32(uint32_t k0, uint32_t k1,
                                           uint32_t x0, uint32_t x1) {
  const uint32_t ks2 = k0 ^ k1 ^ 0x1BD11BDAu;
  x0 += k0; x1 += k1;
#define TFR(r) { x0 += x1; x1 = (x1 << (r)) | (x1 >> (32 - (r))); x1 ^= x0; }
  TFR(13) TFR(15) TFR(26) TFR(6)
  x0 += k1;  x1 += ks2 + 1u;
  TFR(17) TFR(29) TFR(16) TFR(24)
  x0 += ks2; x1 += k0 + 2u;
  TFR(13) TFR(15) TFR(26) TFR(6)
  x0 += k0;  x1 += k1 + 3u;
  TFR(17) TFR(29) TFR(16) TFR(24)
  x0 += k1;  x1 += ks2 + 4u;
  TFR(13) TFR(15) TFR(26) TFR(6)
  x0 += ks2; x1 += k0 + 5u;
#undef TFR
  return {x0, x1};
}

// All keys derive from seed 42 only -> compile-time constants (no kernarg
// aggregate, no byval scratch copy). sk[2t],sk[2t+1] = step_keys[t];
// sk[60..61] = k2 = split(k_init)[1] for the randint lower bits.
struct Keys { uint32_t sk[62]; };

constexpr Keys make_keys() {
  Keys K{};
  const TFOut ki = tf2x32(0u, 42u, 0u, 0u);          // k_init = split(key)[0]
  const TFOut kl = tf2x32(0u, 42u, 0u, 1u);          // k_loop = split(key)[1]
  const TFOut k2 = tf2x32(ki.a, ki.b, 0u, 1u);       // split(k_init)[1]
  K.sk[60] = k2.a; K.sk[61] = k2.b;
  for (uint32_t t = 0; t < (uint32_t)STEPS; ++t) {
    const TFOut s = tf2x32(kl.a, kl.b, 0u, t);       // step_keys[t]
    K.sk[2 * t] = s.a; K.sk[2 * t + 1] = s.b;
  }
  return K;
}

__constant__ Keys KC = make_keys();

// partitionable random_bits element: bits[c] = o0^o1 of block(key, hi=0, lo=c)
__device__ __forceinline__ uint32_t rbits(uint32_t ka, uint32_t kb, uint32_t c) {
  const TFOut r = tf2x32(ka, kb, 0u, c);
  return r.a ^ r.b;
}

// jax uniform f32: bitcast((bits>>9)|0x3f800000) - 1.0 (exact)
__device__ __forceinline__ float bits_to_u(uint32_t b) {
  return __fsub_rn(__uint_as_float((b >> 9) | 0x3f800000u), 1.0f);
}

// XLA:CPU sigmoid, cephes exp fx==0 path, separate mul/add (verified exact).
__device__ __forceinline__ float ref_sigmoid(float v) {
  float a = -v;
  float y = __fadd_rn(__fmul_rn(a, 1.9875691500E-4f), 1.3981999507E-3f);
  y = __fadd_rn(__fmul_rn(y, a), 8.3334519073E-3f);
  y = __fadd_rn(__fmul_rn(y, a), 4.1665795894E-2f);
  y = __fadd_rn(__fmul_rn(y, a), 1.6666665459E-1f);
  y = __fadd_rn(__fmul_rn(y, a), 5.0000001201E-1f);
  float a2 = __fmul_rn(a, a);
  y = __fadd_rn(__fmul_rn(y, a2), a);
  float e = __fadd_rn(1.0f, y);                 // exp(-v)
  return __fdiv_rn(1.0f, __fadd_rn(1.0f, e));   // 1/(1+exp(-v))
}

__global__ __launch_bounds__(TPB, 4)
void rbm_gibbs_kernel(const float* __restrict__ h, const float* __restrict__ W,
                      float* __restrict__ out) {
  // Interleaved W tile: Ws4[m*64+l] = {W[2m][2l], W[2m][2l+1], W[2m+1][2l], W[2m+1][2l+1]}
  // -> one ds_read_b128 per (m, lane) serves both k-rows of both columns.
  __shared__ float4 Ws4[64 * 64];   // 64 KiB

  const int tid = threadIdx.x;
  {
    const float2* Wg2 = reinterpret_cast<const float2*>(W);
    #pragma unroll
    for (int it = 0; it < 4096 / TPB; ++it) {
      const int idx = it * TPB + tid;
      const int m = idx >> 6, l = idx & 63;
      const float2 g0 = Wg2[(2 * m) * 64 + l];
      const float2 g1 = Wg2[(2 * m + 1) * 64 + l];
      Ws4[idx] = make_float4(g0.x, g0.y, g1.x, g1.y);
    }
  }
  __syncthreads();

  const int lane = tid & 63;
  const int wid  = blockIdx.x * WAVES_PB + (tid >> 6);    // [0, NWAVES)
  const uint32_t cb = (uint32_t)wid * (uint32_t)(R * LATENT);  // < 2^26
  const int j0 = 2 * lane;                                // lane's even column
  const float h0 = h[j0], h1 = h[j0 + 1];

  // ---- z0: randint lower bits & 1; bit l of mE[q]/mO[q] = z[row q][col 2l / 2l+1]
  unsigned long long mE[R], mO[R];
  {
    const uint32_t ka = KC.sk[60], kb = KC.sk[61];
    #pragma unroll
    for (int q = 0; q < R; ++q) {
      const uint32_t c = cb + (uint32_t)(q * LATENT) + (uint32_t)j0;
      const uint32_t bE = rbits(ka, kb, c);
      const uint32_t bO = rbits(ka, kb, c + 1u);
      mE[q] = __ballot((int)(bE & 1u));
      mO[q] = __ballot((int)(bO & 1u));
    }
  }

  #pragma unroll 1
  for (int t = 0; t < STEPS; ++t) {
    // ---- dot: strict k-ascending FMA chain from 0 (bitwise = verified kernel)
    float acc[R][2];
    #pragma unroll
    for (int q = 0; q < R; ++q) { acc[q][0] = 0.f; acc[q][1] = 0.f; }

    #pragma unroll 4
    for (int m = 0; m < 64; ++m) {
      const float4 w = Ws4[m * 64 + lane];
      #pragma unroll
      for (int q = 0; q < R; ++q) {
        const float fE = ((mE[q] >> m) & 1ull) ? 1.0f : 0.0f;  // wave-uniform
        const float fO = ((mO[q] >> m) & 1ull) ? 1.0f : 0.0f;
        acc[q][0] = __fmaf_rn(fE, w.x, acc[q][0]);
        acc[q][1] = __fmaf_rn(fE, w.y, acc[q][1]);
        acc[q][0] = __fmaf_rn(fO, w.z, acc[q][0]);
        acc[q][1] = __fmaf_rn(fO, w.w, acc[q][1]);
      }
    }

    // ---- uniforms + Bernoulli update
    const uint32_t sa = KC.sk[2 * t], sb = KC.sk[2 * t + 1];
    #pragma unroll
    for (int q = 0; q < R; ++q) {
      const uint32_t c = cb + (uint32_t)(q * LATENT) + (uint32_t)j0;
      const uint32_t uE = rbits(sa, sb, c);
      const uint32_t uO = rbits(sa, sb, c + 1u);
      const float pE = ref_sigmoid(__fadd_rn(h0, acc[q][0]));
      const float pO = ref_sigmoid(__fadd_rn(h1, acc[q][1]));
      mE[q] = __ballot((int)(bits_to_u(uE) < pE));
      mO[q] = __ballot((int)(bits_to_u(uO) < pO));
    }
  }

  // ---- write z_final: 4 consecutive rows per wave, float2 per lane (coalesced)
  float2* out2 = reinterpret_cast<float2*>(out);
  #pragma unroll
  for (int q = 0; q < R; ++q) {
    float2 z;
    z.x = (float)((mE[q] >> lane) & 1ull);
    z.y = (float)((mO[q] >> lane) & 1ull);
    out2[(size_t)(wid * R + q) * 64 + lane] = z;
  }
}

extern "C" void kernel_launch(void* const* d_in, const int* in_sizes, int n_in,
                              void* d_out, int out_size, void* d_ws, size_t ws_size,
                              hipStream_t stream) {
  const float* h = (const float*)d_in[0];
  const float* W = (const float*)d_in[1];
  float* out = (float*)d_out;
  rbm_gibbs_kernel<<<NBLOCKS, TPB, 0, stream>>>(h, W, out);
}

// Round 7
// 14654.256 us; speedup vs baseline: 2.7661x; 1.0331x over previous
//
#include <hip/hip_runtime.h>
#include <cstdint>

// Verified bit-exact (round 5/6, absmax 0.0): partitionable threefry split
// (block(key,0,i)), randint(0,2)=lower_bits&1, uniform=(bits>>9)|0x3f800000 - 1,
// dot = strict k-ascending __fmaf_rn chain from 0, sigmoid = 1/(1+exp(-x)) with
// cephes exp separate mul/add on the fx==0 path. DO NOT change any arithmetic.

constexpr int LATENT = 128;
constexpr int NS = 524288;
constexpr int STEPS = 30;
constexpr int R = 4;                       // rows per wave
constexpr int TPB = 1024;                  // 16 waves/block; 2 blocks/CU (LDS) -> 32 waves/CU
constexpr int WAVES_PB = TPB / 64;
constexpr int NWAVES = NS / R;             // 131072
constexpr int NBLOCKS = NWAVES / WAVES_PB; // 8192

// ---------------- threefry2x32, 20 rounds, exactly jax's schedule ----------------
struct TFOut { uint32_t a, b; };

__host__ __device__ constexpr TFOut tf2x32(uint32_t k0, uint32_t k1,
                                           uint32_t x0, uint32_t x1) {
  const uint32_t ks2 = k0 ^ k1 ^ 0x1BD11BDAu;
  x0 += k0; x1 += k1;
#define TFR(r) { x0 += x1; x1 = (x1 << (r)) | (x1 >> (32 - (r))); x1 ^= x0; }
  TFR(13) TFR(15) TFR(26) TFR(6)
  x0 += k1;  x1 += ks2 + 1u;
  TFR(17) TFR(29) TFR(16) TFR(24)
  x0 += ks2; x1 += k0 + 2u;
  TFR(13) TFR(15) TFR(26) TFR(6)
  x0 += k0;  x1 += k1 + 3u;
  TFR(17) TFR(29) TFR(16) TFR(24)
  x0 += k1;  x1 += ks2 + 4u;
  TFR(13) TFR(15) TFR(26) TFR(6)
  x0 += ks2; x1 += k0 + 5u;
#undef TFR
  return {x0, x1};
}

// All keys derive from seed 42 -> compile-time constants.
// sk[2t],sk[2t+1] = step_keys[t]; sk[60..61] = split(k_init)[1] (randint bits).
struct Keys { uint32_t sk[62]; };

constexpr Keys make_keys() {
  Keys K{};
  const TFOut ki = tf2x32(0u, 42u, 0u, 0u);          // k_init = split(key)[0]
  const TFOut kl = tf2x32(0u, 42u, 0u, 1u);          // k_loop = split(key)[1]
  const TFOut k2 = tf2x32(ki.a, ki.b, 0u, 1u);       // split(k_init)[1]
  K.sk[60] = k2.a; K.sk[61] = k2.b;
  for (uint32_t t = 0; t < (uint32_t)STEPS; ++t) {
    const TFOut s = tf2x32(kl.a, kl.b, 0u, t);       // step_keys[t]
    K.sk[2 * t] = s.a; K.sk[2 * t + 1] = s.b;
  }
  return K;
}

__constant__ Keys KC = make_keys();

// partitionable random_bits element: bits[c] = o0^o1 of block(key, hi=0, lo=c)
__device__ __forceinline__ uint32_t rbits(uint32_t ka, uint32_t kb, uint32_t c) {
  const TFOut r = tf2x32(ka, kb, 0u, c);
  return r.a ^ r.b;
}

// jax uniform f32: bitcast((bits>>9)|0x3f800000) - 1.0 (exact)
__device__ __forceinline__ float bits_to_u(uint32_t b) {
  return __fsub_rn(__uint_as_float((b >> 9) | 0x3f800000u), 1.0f);
}

// XLA:CPU sigmoid, cephes exp fx==0 path, separate mul/add (verified exact).
__device__ __forceinline__ float ref_sigmoid(float v) {
  float a = -v;
  float y = __fadd_rn(__fmul_rn(a, 1.9875691500E-4f), 1.3981999507E-3f);
  y = __fadd_rn(__fmul_rn(y, a), 8.3334519073E-3f);
  y = __fadd_rn(__fmul_rn(y, a), 4.1665795894E-2f);
  y = __fadd_rn(__fmul_rn(y, a), 1.6666665459E-1f);
  y = __fadd_rn(__fmul_rn(y, a), 5.0000001201E-1f);
  float a2 = __fmul_rn(a, a);
  y = __fadd_rn(__fmul_rn(y, a2), a);
  float e = __fadd_rn(1.0f, y);                 // exp(-v)
  return __fdiv_rn(1.0f, __fadd_rn(1.0f, e));   // 1/(1+exp(-v))
}

// Wave-uniform ballot halves forced into SGPRs: selects in the FMA loop become
// SALU (s_lshr/s_cselect), issuing in parallel with the VALU FMAs.
__device__ __forceinline__ void ballot_scalar(int pred, uint32_t& lo, uint32_t& hi) {
  const unsigned long long b = __ballot(pred);
  lo = __builtin_amdgcn_readfirstlane((uint32_t)b);
  hi = __builtin_amdgcn_readfirstlane((uint32_t)(b >> 32));
}

__global__ __launch_bounds__(TPB, 8)   // 8 waves/EU -> VGPR cap 64, 32 waves/CU
void rbm_gibbs_kernel(const float* __restrict__ h, const float* __restrict__ W,
                      float* __restrict__ out) {
  // Interleaved W tile: Ws4[m*64+l] = {W[2m][2l], W[2m][2l+1], W[2m+1][2l], W[2m+1][2l+1]}
  __shared__ float4 Ws4[64 * 64];   // 64 KiB

  const int tid = threadIdx.x;
  {
    const float2* Wg2 = reinterpret_cast<const float2*>(W);
    #pragma unroll
    for (int it = 0; it < 4096 / TPB; ++it) {
      const int idx = it * TPB + tid;
      const int m = idx >> 6, l = idx & 63;
      const float2 g0 = Wg2[(2 * m) * 64 + l];
      const float2 g1 = Wg2[(2 * m + 1) * 64 + l];
      Ws4[idx] = make_float4(g0.x, g0.y, g1.x, g1.y);
    }
  }
  __syncthreads();

  const int lane = tid & 63;
  const int wid  = blockIdx.x * WAVES_PB + (tid >> 6);        // [0, NWAVES)
  const uint32_t cb = (uint32_t)wid * (uint32_t)(R * LATENT); // < 2^26
  const int j0 = 2 * lane;
  const float h0 = h[j0], h1 = h[j0 + 1];

  // ---- z0: randint lower bits & 1 ; bit l of E/O mask = z[row q][col 2l / 2l+1]
  uint32_t mElo[R], mEhi[R], mOlo[R], mOhi[R];
  {
    const uint32_t ka = KC.sk[60], kb = KC.sk[61];
    #pragma unroll
    for (int q = 0; q < R; ++q) {
      const uint32_t c = cb + (uint32_t)(q * LATENT) + (uint32_t)j0;
      ballot_scalar((int)(rbits(ka, kb, c) & 1u),      mElo[q], mEhi[q]);
      ballot_scalar((int)(rbits(ka, kb, c + 1u) & 1u), mOlo[q], mOhi[q]);
    }
  }

  #pragma unroll 1
  for (int t = 0; t < STEPS; ++t) {
    // ---- dot: strict k-ascending FMA chain from 0 (bitwise = verified kernel)
    float acc[R][2];
    #pragma unroll
    for (int q = 0; q < R; ++q) { acc[q][0] = 0.f; acc[q][1] = 0.f; }

    #pragma unroll 4
    for (int m = 0; m < 32; ++m) {
      const float4 w = Ws4[m * 64 + lane];
      #pragma unroll
      for (int q = 0; q < R; ++q) {
        const float fE = ((mElo[q] >> m) & 1u) ? 1.0f : 0.0f;  // wave-uniform (SGPR)
        const float fO = ((mOlo[q] >> m) & 1u) ? 1.0f : 0.0f;
        acc[q][0] = __fmaf_rn(fE, w.x, acc[q][0]);
        acc[q][1] = __fmaf_rn(fE, w.y, acc[q][1]);
        acc[q][0] = __fmaf_rn(fO, w.z, acc[q][0]);
        acc[q][1] = __fmaf_rn(fO, w.w, acc[q][1]);
      }
    }
    #pragma unroll 4
    for (int m = 32; m < 64; ++m) {
      const float4 w = Ws4[m * 64 + lane];
      const int mm = m - 32;
      #pragma unroll
      for (int q = 0; q < R; ++q) {
        const float fE = ((mEhi[q] >> mm) & 1u) ? 1.0f : 0.0f;
        const float fO = ((mOhi[q] >> mm) & 1u) ? 1.0f : 0.0f;
        acc[q][0] = __fmaf_rn(fE, w.x, acc[q][0]);
        acc[q][1] = __fmaf_rn(fE, w.y, acc[q][1]);
        acc[q][0] = __fmaf_rn(fO, w.z, acc[q][0]);
        acc[q][1] = __fmaf_rn(fO, w.w, acc[q][1]);
      }
    }

    // ---- uniforms + Bernoulli update
    const uint32_t sa = KC.sk[2 * t], sb = KC.sk[2 * t + 1];
    #pragma unroll
    for (int q = 0; q < R; ++q) {
      const uint32_t c = cb + (uint32_t)(q * LATENT) + (uint32_t)j0;
      const uint32_t uE = rbits(sa, sb, c);
      const uint32_t uO = rbits(sa, sb, c + 1u);
      const float pE = ref_sigmoid(__fadd_rn(h0, acc[q][0]));
      const float pO = ref_sigmoid(__fadd_rn(h1, acc[q][1]));
      ballot_scalar((int)(bits_to_u(uE) < pE), mElo[q], mEhi[q]);
      ballot_scalar((int)(bits_to_u(uO) < pO), mOlo[q], mOhi[q]);
    }
  }

  // ---- write z_final: R consecutive rows per wave, float2 per lane (coalesced)
  float2* out2 = reinterpret_cast<float2*>(out);
  #pragma unroll
  for (int q = 0; q < R; ++q) {
    float2 z;
    z.x = (float)((q < 0 ? 0u : ((lane < 32 ? mElo[q] : mEhi[q]) >> (lane & 31))) & 1u);
    z.y = (float)(((lane < 32 ? mOlo[q] : mOhi[q]) >> (lane & 31)) & 1u);
    out2[(size_t)(wid * R + q) * 64 + lane] = z;
  }
}

extern "C" void kernel_launch(void* const* d_in, const int* in_sizes, int n_in,
                              void* d_out, int out_size, void* d_ws, size_t ws_size,
                              hipStream_t stream) {
  const float* h = (const float*)d_in[0];
  const float* W = (const float*)d_in[1];
  float* out = (float*)d_out;
  rbm_gibbs_kernel<<<NBLOCKS, TPB, 0, stream>>>(h, W, out);
}

// Round 10
// 10538.396 us; speedup vs baseline: 3.8465x; 1.3906x over previous
//
#include <hip/hip_runtime.h>
#include <cstdint>
#include <utility>

// Verified bit-exact (rounds 5-7, absmax 0.0): partitionable threefry split
// (block(key,0,i)), randint(0,2)=lower_bits&1, uniform=(bits>>9)|0x3f800000 - 1,
// dot = strict k-ascending fma chain from 0, sigmoid = 1/(1+exp(-x)) with
// cephes exp separate mul/add on the fx==0 path. DO NOT change any arithmetic.

constexpr int LATENT = 128;
constexpr int NS = 524288;
constexpr int STEPS = 30;
constexpr int R = 4;                       // rows per wave
constexpr int TPB = 1024;                  // 16 waves/block; 2 blocks/CU -> 32 waves/CU
constexpr int WAVES_PB = TPB / 64;
constexpr int NWAVES = NS / R;             // 131072
constexpr int NBLOCKS = NWAVES / WAVES_PB; // 8192

typedef float f32x2 __attribute__((ext_vector_type(2)));

// ---------------- compile-time unroll helper (constexpr index for asm "n") ----
template <typename F, int... I>
__device__ __forceinline__ void unroll_impl(F&& f, std::integer_sequence<int, I...>) {
  (f(std::integral_constant<int, I>{}), ...);
}
template <int N, typename F>
__device__ __forceinline__ void unroll_n(F&& f) {
  unroll_impl(static_cast<F&&>(f), std::make_integer_sequence<int, N>{});
}

// ---------------- threefry2x32, 20 rounds, exactly jax's schedule ----------------
struct TFOut { uint32_t a, b; };

__host__ __device__ constexpr TFOut tf2x32_ct(uint32_t k0, uint32_t k1,
                                              uint32_t x0, uint32_t x1) {
  const uint32_t ks2 = k0 ^ k1 ^ 0x1BD11BDAu;
  x0 += k0; x1 += k1;
#define TFR(r) { x0 += x1; x1 = (x1 << (r)) | (x1 >> (32 - (r))); x1 ^= x0; }
  TFR(13) TFR(15) TFR(26) TFR(6)
  x0 += k1;  x1 += ks2 + 1u;
  TFR(17) TFR(29) TFR(16) TFR(24)
  x0 += ks2; x1 += k0 + 2u;
  TFR(13) TFR(15) TFR(26) TFR(6)
  x0 += k0;  x1 += k1 + 3u;
  TFR(17) TFR(29) TFR(16) TFR(24)
  x0 += k1;  x1 += ks2 + 4u;
  TFR(13) TFR(15) TFR(26) TFR(6)
  x0 += ks2; x1 += k0 + 5u;
#undef TFR
  return {x0, x1};
}

// Device version with guaranteed 1-op rotates (v_alignbit_b32).
__device__ __forceinline__ uint32_t rotl_hw(uint32_t x, int r) {
  return __builtin_amdgcn_alignbit(x, x, (uint32_t)(32 - r));
}
__device__ __forceinline__ TFOut tf2x32_dev(uint32_t k0, uint32_t k1,
                                            uint32_t x0, uint32_t x1) {
  const uint32_t ks2 = k0 ^ k1 ^ 0x1BD11BDAu;
  x0 += k0; x1 += k1;
#define TFRD(r) { x0 += x1; x1 = rotl_hw(x1, r); x1 ^= x0; }
  TFRD(13) TFRD(15) TFRD(26) TFRD(6)
  x0 += k1;  x1 += ks2 + 1u;
  TFRD(17) TFRD(29) TFRD(16) TFRD(24)
  x0 += ks2; x1 += k0 + 2u;
  TFRD(13) TFRD(15) TFRD(26) TFRD(6)
  x0 += k0;  x1 += k1 + 3u;
  TFRD(17) TFRD(29) TFRD(16) TFRD(24)
  x0 += k1;  x1 += ks2 + 4u;
  TFRD(13) TFRD(15) TFRD(26) TFRD(6)
  x0 += ks2; x1 += k0 + 5u;
#undef TFRD
  return {x0, x1};
}

// All keys derive from seed 42 -> compile-time constants.
struct Keys { uint32_t sk[62]; };
constexpr Keys make_keys() {
  Keys K{};
  const TFOut ki = tf2x32_ct(0u, 42u, 0u, 0u);        // k_init = split(key)[0]
  const TFOut kl = tf2x32_ct(0u, 42u, 0u, 1u);        // k_loop = split(key)[1]
  const TFOut k2 = tf2x32_ct(ki.a, ki.b, 0u, 1u);     // split(k_init)[1]
  K.sk[60] = k2.a; K.sk[61] = k2.b;
  for (uint32_t t = 0; t < (uint32_t)STEPS; ++t) {
    const TFOut s = tf2x32_ct(kl.a, kl.b, 0u, t);     // step_keys[t]
    K.sk[2 * t] = s.a; K.sk[2 * t + 1] = s.b;
  }
  return K;
}
__constant__ Keys KC = make_keys();

// partitionable random_bits element: bits[c] = o0^o1 of block(key, hi=0, lo=c)
__device__ __forceinline__ uint32_t rbits(uint32_t ka, uint32_t kb, uint32_t c) {
  const TFOut r = tf2x32_dev(ka, kb, 0u, c);
  return r.a ^ r.b;
}

// jax uniform f32: bitcast((bits>>9)|0x3f800000) - 1.0 (exact)
__device__ __forceinline__ float bits_to_u(uint32_t b) {
  return __fsub_rn(__uint_as_float((b >> 9) | 0x3f800000u), 1.0f);
}

// XLA:CPU sigmoid, cephes exp fx==0 path, separate mul/add (verified exact).
__device__ __forceinline__ float ref_sigmoid(float v) {
  float a = -v;
  float y = __fadd_rn(__fmul_rn(a, 1.9875691500E-4f), 1.3981999507E-3f);
  y = __fadd_rn(__fmul_rn(y, a), 8.3334519073E-3f);
  y = __fadd_rn(__fmul_rn(y, a), 4.1665795894E-2f);
  y = __fadd_rn(__fmul_rn(y, a), 1.6666665459E-1f);
  y = __fadd_rn(__fmul_rn(y, a), 5.0000001201E-1f);
  float a2 = __fmul_rn(a, a);
  y = __fadd_rn(__fmul_rn(y, a2), a);
  float e = __fadd_rn(1.0f, y);                 // exp(-v)
  return __fdiv_rn(1.0f, __fadd_rn(1.0f, e));   // 1/(1+exp(-v))
}

// Wave-uniform ballot halves into SGPRs.
__device__ __forceinline__ void ballot_scalar(int pred, uint32_t& lo, uint32_t& hi) {
  const unsigned long long b = __ballot(pred);
  lo = __builtin_amdgcn_readfirstlane((uint32_t)b);
  hi = __builtin_amdgcn_readfirstlane((uint32_t)(b >> 32));
}

// bit B of mask -> SGPR pair {1.0f,1.0f} or {0,0}: exactly 2 SALU ops.
template <int B>
__device__ __forceinline__ uint64_t sel_bit2(uint32_t mask, uint64_t one2) {
  uint64_t f2;
  asm("s_bitcmp1_b32 %1, %3\n\t"
      "s_cselect_b64 %0, %2, 0"
      : "=s"(f2) : "s"(mask), "s"(one2), "n"(B) : "scc");
  return f2;
}

// acc (v-pair) += f2 (s-pair, {f,f}) * w (v-pair): one v_pk_fma_f32,
// each half an IEEE fmaf_rn -> bit-exact vs two scalar __fmaf_rn.
__device__ __forceinline__ void pk_fma_pair(f32x2& acc, uint64_t f2, f32x2 w) {
  asm("v_pk_fma_f32 %0, %2, %1, %0"
      : "+v"(acc) : "v"(w), "s"(f2));
}

__global__ __launch_bounds__(TPB, 8)
void rbm_gibbs_kernel(const float* __restrict__ h, const float* __restrict__ W,
                      float* __restrict__ out) {
  // WsA[m*64+l] = {W[2m][2l],   W[2m][2l+1]}   (k even)
  // WsB[m*64+l] = {W[2m+1][2l], W[2m+1][2l+1]} (k odd)
  __shared__ f32x2 WsA[64 * 64];   // 32 KiB
  __shared__ f32x2 WsB[64 * 64];   // 32 KiB

  const int tid = threadIdx.x;
  {
    const float2* Wg2 = reinterpret_cast<const float2*>(W);
    #pragma unroll
    for (int it = 0; it < 4096 / TPB; ++it) {
      const int idx = it * TPB + tid;
      const int m = idx >> 6, l = idx & 63;
      const float2 g0 = Wg2[(2 * m) * 64 + l];
      const float2 g1 = Wg2[(2 * m + 1) * 64 + l];
      WsA[idx] = f32x2{g0.x, g0.y};
      WsB[idx] = f32x2{g1.x, g1.y};
    }
  }
  __syncthreads();

  const int lane = tid & 63;
  const int wid  = blockIdx.x * WAVES_PB + (tid >> 6);        // [0, NWAVES)
  const uint32_t cb = (uint32_t)wid * (uint32_t)(R * LATENT); // < 2^26
  const int j0 = 2 * lane;
  const float h0 = h[j0], h1 = h[j0 + 1];
  const uint64_t one2 = 0x3f8000003f800000ull;                // {1.0f, 1.0f}

  // ---- z0: randint lower bits & 1 ; bit l of E/O mask = z[row q][col 2l / 2l+1]
  uint32_t mElo[R], mEhi[R], mOlo[R], mOhi[R];
  {
    const uint32_t ka = KC.sk[60], kb = KC.sk[61];
    #pragma unroll
    for (int q = 0; q < R; ++q) {
      const uint32_t c = cb + (uint32_t)(q * LATENT) + (uint32_t)j0;
      ballot_scalar((int)(rbits(ka, kb, c) & 1u),      mElo[q], mEhi[q]);
      ballot_scalar((int)(rbits(ka, kb, c + 1u) & 1u), mOlo[q], mOhi[q]);
    }
  }

  #pragma unroll 1
  for (int t = 0; t < STEPS; ++t) {
    // ---- dot: strict k-ascending chain from 0; k=2m via E-bit m, k=2m+1 via O-bit m.
    // Packed over the column pair (2l, 2l+1): lo/hi are independent chains.
    f32x2 acc[R];
    #pragma unroll
    for (int q = 0; q < R; ++q) acc[q] = f32x2{0.f, 0.f};

    unroll_n<32>([&](auto MC) {            // m = 0..31: lo mask halves
      constexpr int m = MC.value;
      const f32x2 wA = WsA[m * 64 + lane];
      const f32x2 wB = WsB[m * 64 + lane];
      #pragma unroll
      for (int q = 0; q < R; ++q) {
        pk_fma_pair(acc[q], sel_bit2<m>(mElo[q], one2), wA);
        pk_fma_pair(acc[q], sel_bit2<m>(mOlo[q], one2), wB);
      }
    });
    unroll_n<32>([&](auto MC) {            // m = 32..63: hi mask halves
      constexpr int m = MC.value;
      const f32x2 wA = WsA[(m + 32) * 64 + lane];
      const f32x2 wB = WsB[(m + 32) * 64 + lane];
      #pragma unroll
      for (int q = 0; q < R; ++q) {
        pk_fma_pair(acc[q], sel_bit2<m>(mEhi[q], one2), wA);
        pk_fma_pair(acc[q], sel_bit2<m>(mOhi[q], one2), wB);
      }
    });

    // ---- uniforms + Bernoulli update
    const uint32_t sa = KC.sk[2 * t], sb = KC.sk[2 * t + 1];
    #pragma unroll
    for (int q = 0; q < R; ++q) {
      const uint32_t c = cb + (uint32_t)(q * LATENT) + (uint32_t)j0;
      const uint32_t uE = rbits(sa, sb, c);
      const uint32_t uO = rbits(sa, sb, c + 1u);
      const float pE = ref_sigmoid(__fadd_rn(h0, acc[q].x));
      const float pO = ref_sigmoid(__fadd_rn(h1, acc[q].y));
      ballot_scalar((int)(bits_to_u(uE) < pE), mElo[q], mEhi[q]);
      ballot_scalar((int)(bits_to_u(uO) < pO), mOlo[q], mOhi[q]);
    }
  }

  // ---- write z_final: R consecutive rows per wave, float2 per lane (coalesced)
  float2* out2 = reinterpret_cast<float2*>(out);
  #pragma unroll
  for (int q = 0; q < R; ++q) {
    float2 z;
    z.x = (float)(((lane < 32 ? mElo[q] : mEhi[q]) >> (lane & 31)) & 1u);
    z.y = (float)(((lane < 32 ? mOlo[q] : mOhi[q]) >> (lane & 31)) & 1u);
    out2[(size_t)(wid * R + q) * 64 + lane] = z;
  }
}

extern "C" void kernel_launch(void* const* d_in, const int* in_sizes, int n_in,
                              void* d_out, int out_size, void* d_ws, size_t ws_size,
                              hipStream_t stream) {
  const float* h = (const float*)d_in[0];
  const float* W = (const float*)d_in[1];
  float* out = (float*)d_out;
  rbm_gibbs_kernel<<<NBLOCKS, TPB, 0, stream>>>(h, W, out);
}

// Round 11
// 9357.738 us; speedup vs baseline: 4.3318x; 1.1262x over previous
//
#include <hip/hip_runtime.h>
#include <cstdint>
#include <utility>

// Verified bit-exact (rounds 5-10, absmax 0.0): partitionable threefry split
// (block(key,0,i)), randint(0,2)=lower_bits&1, uniform=(bits>>9)|0x3f800000 - 1,
// dot = strict k-ascending fma chain from 0, sigmoid = 1/(1+exp(-x)) with
// cephes exp separate mul/add on the fx==0 path. DO NOT change any arithmetic.
//
// Perf model (r10 post-mortem): v_pk_fma_f32 is quarter-rate on gfx950 -> use
// scalar v_fmac_f32. One SALU per CU -> split bit->float selects ~25% VALU
// (row q=0) / 75% SALU (rows 1-3) to balance the two pipes.

constexpr int LATENT = 128;
constexpr int NS = 524288;
constexpr int STEPS = 30;
constexpr int R = 4;                       // rows per wave
constexpr int TPB = 1024;                  // 16 waves/block; 2 blocks/CU -> 32 waves/CU
constexpr int WAVES_PB = TPB / 64;
constexpr int NWAVES = NS / R;             // 131072
constexpr int NBLOCKS = NWAVES / WAVES_PB; // 8192

typedef float f32x2 __attribute__((ext_vector_type(2)));

// ---------------- compile-time unroll helper (constexpr index for asm "n") ----
template <typename F, int... I>
__device__ __forceinline__ void unroll_impl(F&& f, std::integer_sequence<int, I...>) {
  (f(std::integral_constant<int, I>{}), ...);
}
template <int N, typename F>
__device__ __forceinline__ void unroll_n(F&& f) {
  unroll_impl(static_cast<F&&>(f), std::make_integer_sequence<int, N>{});
}

// ---------------- threefry2x32, 20 rounds, exactly jax's schedule ----------------
struct TFOut { uint32_t a, b; };

__host__ __device__ constexpr TFOut tf2x32_ct(uint32_t k0, uint32_t k1,
                                              uint32_t x0, uint32_t x1) {
  const uint32_t ks2 = k0 ^ k1 ^ 0x1BD11BDAu;
  x0 += k0; x1 += k1;
#define TFR(r) { x0 += x1; x1 = (x1 << (r)) | (x1 >> (32 - (r))); x1 ^= x0; }
  TFR(13) TFR(15) TFR(26) TFR(6)
  x0 += k1;  x1 += ks2 + 1u;
  TFR(17) TFR(29) TFR(16) TFR(24)
  x0 += ks2; x1 += k0 + 2u;
  TFR(13) TFR(15) TFR(26) TFR(6)
  x0 += k0;  x1 += k1 + 3u;
  TFR(17) TFR(29) TFR(16) TFR(24)
  x0 += k1;  x1 += ks2 + 4u;
  TFR(13) TFR(15) TFR(26) TFR(6)
  x0 += ks2; x1 += k0 + 5u;
#undef TFR
  return {x0, x1};
}

// Device version with guaranteed 1-op rotates (v_alignbit_b32).
__device__ __forceinline__ uint32_t rotl_hw(uint32_t x, int r) {
  return __builtin_amdgcn_alignbit(x, x, (uint32_t)(32 - r));
}
__device__ __forceinline__ TFOut tf2x32_dev(uint32_t k0, uint32_t k1,
                                            uint32_t x0, uint32_t x1) {
  const uint32_t ks2 = k0 ^ k1 ^ 0x1BD11BDAu;
  x0 += k0; x1 += k1;
#define TFRD(r) { x0 += x1; x1 = rotl_hw(x1, r); x1 ^= x0; }
  TFRD(13) TFRD(15) TFRD(26) TFRD(6)
  x0 += k1;  x1 += ks2 + 1u;
  TFRD(17) TFRD(29) TFRD(16) TFRD(24)
  x0 += ks2; x1 += k0 + 2u;
  TFRD(13) TFRD(15) TFRD(26) TFRD(6)
  x0 += k0;  x1 += k1 + 3u;
  TFRD(17) TFRD(29) TFRD(16) TFRD(24)
  x0 += k1;  x1 += ks2 + 4u;
  TFRD(13) TFRD(15) TFRD(26) TFRD(6)
  x0 += ks2; x1 += k0 + 5u;
#undef TFRD
  return {x0, x1};
}

// All keys derive from seed 42 -> compile-time constants.
struct Keys { uint32_t sk[62]; };
constexpr Keys make_keys() {
  Keys K{};
  const TFOut ki = tf2x32_ct(0u, 42u, 0u, 0u);        // k_init = split(key)[0]
  const TFOut kl = tf2x32_ct(0u, 42u, 0u, 1u);        // k_loop = split(key)[1]
  const TFOut k2 = tf2x32_ct(ki.a, ki.b, 0u, 1u);     // split(k_init)[1]
  K.sk[60] = k2.a; K.sk[61] = k2.b;
  for (uint32_t t = 0; t < (uint32_t)STEPS; ++t) {
    const TFOut s = tf2x32_ct(kl.a, kl.b, 0u, t);     // step_keys[t]
    K.sk[2 * t] = s.a; K.sk[2 * t + 1] = s.b;
  }
  return K;
}
__constant__ Keys KC = make_keys();

// partitionable random_bits element: bits[c] = o0^o1 of block(key, hi=0, lo=c)
__device__ __forceinline__ uint32_t rbits(uint32_t ka, uint32_t kb, uint32_t c) {
  const TFOut r = tf2x32_dev(ka, kb, 0u, c);
  return r.a ^ r.b;
}

// jax uniform f32: bitcast((bits>>9)|0x3f800000) - 1.0 (exact)
__device__ __forceinline__ float bits_to_u(uint32_t b) {
  return __fsub_rn(__uint_as_float((b >> 9) | 0x3f800000u), 1.0f);
}

// XLA:CPU sigmoid, cephes exp fx==0 path, separate mul/add (verified exact).
__device__ __forceinline__ float ref_sigmoid(float v) {
  float a = -v;
  float y = __fadd_rn(__fmul_rn(a, 1.9875691500E-4f), 1.3981999507E-3f);
  y = __fadd_rn(__fmul_rn(y, a), 8.3334519073E-3f);
  y = __fadd_rn(__fmul_rn(y, a), 4.1665795894E-2f);
  y = __fadd_rn(__fmul_rn(y, a), 1.6666665459E-1f);
  y = __fadd_rn(__fmul_rn(y, a), 5.0000001201E-1f);
  float a2 = __fmul_rn(a, a);
  y = __fadd_rn(__fmul_rn(y, a2), a);
  float e = __fadd_rn(1.0f, y);                 // exp(-v)
  return __fdiv_rn(1.0f, __fadd_rn(1.0f, e));   // 1/(1+exp(-v))
}

// Wave-uniform ballot halves into SGPRs.
__device__ __forceinline__ void ballot_scalar(int pred, uint32_t& lo, uint32_t& hi) {
  const unsigned long long b = __ballot(pred);
  lo = __builtin_amdgcn_readfirstlane((uint32_t)b);
  hi = __builtin_amdgcn_readfirstlane((uint32_t)(b >> 32));
}

// SALU select: bit B of mask -> 0x3f800000 or 0 in an SGPR (2 SALU ops).
// Exact: 0x3f800000 has 23 low zero bits, s_mul by 0/1 is exact.
template <int B>
__device__ __forceinline__ float sel_bit_salu(uint32_t mask) {
  uint32_t f;
  asm("s_bfe_u32 %0, %1, %2\n\t"
      "s_mul_i32 %0, %0, 0x3f800000"
      : "=s"(f) : "s"(mask), "n"(B | (1 << 16)) : "scc");
  return __uint_as_float(f);
}

// VALU select: bit B of mask -> 1.0f/0.0f in a VGPR (2 VALU ops).
template <int B>
__device__ __forceinline__ float sel_bit_valu(uint32_t mask) {
  uint32_t b; float f;
  asm("v_bfe_u32 %0, %1, %2, 1" : "=v"(b) : "s"(mask), "n"(B));
  asm("v_cvt_f32_u32 %0, %1" : "=v"(f) : "v"(b));
  return f;
}

// acc += f * w : scalar v_fmac_f32 (full-rate), f from SGPR or VGPR.
__device__ __forceinline__ void fmac_s(float& acc, float f, float w) {
  asm("v_fmac_f32 %0, %1, %2" : "+v"(acc) : "s"(f), "v"(w));
}
__device__ __forceinline__ void fmac_v(float& acc, float f, float w) {
  asm("v_fmac_f32 %0, %1, %2" : "+v"(acc) : "v"(f), "v"(w));
}

__global__ __launch_bounds__(TPB, 8)
void rbm_gibbs_kernel(const float* __restrict__ h, const float* __restrict__ W,
                      float* __restrict__ out) {
  // WsA[m*64+l] = {W[2m][2l],   W[2m][2l+1]}   (k even)
  // WsB[m*64+l] = {W[2m+1][2l], W[2m+1][2l+1]} (k odd)
  __shared__ f32x2 WsA[64 * 64];   // 32 KiB
  __shared__ f32x2 WsB[64 * 64];   // 32 KiB

  const int tid = threadIdx.x;
  {
    const float2* Wg2 = reinterpret_cast<const float2*>(W);
    #pragma unroll
    for (int it = 0; it < 4096 / TPB; ++it) {
      const int idx = it * TPB + tid;
      const int m = idx >> 6, l = idx & 63;
      const float2 g0 = Wg2[(2 * m) * 64 + l];
      const float2 g1 = Wg2[(2 * m + 1) * 64 + l];
      WsA[idx] = f32x2{g0.x, g0.y};
      WsB[idx] = f32x2{g1.x, g1.y};
    }
  }
  __syncthreads();

  const int lane = tid & 63;
  const int wid  = blockIdx.x * WAVES_PB + (tid >> 6);        // [0, NWAVES)
  const uint32_t cb = (uint32_t)wid * (uint32_t)(R * LATENT); // < 2^26
  const int j0 = 2 * lane;
  const float h0 = h[j0], h1 = h[j0 + 1];

  // ---- z0: randint lower bits & 1 ; bit l of E/O mask = z[row q][col 2l / 2l+1]
  uint32_t mElo[R], mEhi[R], mOlo[R], mOhi[R];
  {
    const uint32_t ka = KC.sk[60], kb = KC.sk[61];
    #pragma unroll
    for (int q = 0; q < R; ++q) {
      const uint32_t c = cb + (uint32_t)(q * LATENT) + (uint32_t)j0;
      ballot_scalar((int)(rbits(ka, kb, c) & 1u),      mElo[q], mEhi[q]);
      ballot_scalar((int)(rbits(ka, kb, c + 1u) & 1u), mOlo[q], mOhi[q]);
    }
  }

  #pragma unroll 1
  for (int t = 0; t < STEPS; ++t) {
    // ---- dot: strict k-ascending chain from 0; k=2m via E-bit m, k=2m+1 via O-bit m.
    // Row q=0 selects on VALU, rows 1-3 on SALU (pipe balance).
    float ax[R], ay[R];
    #pragma unroll
    for (int q = 0; q < R; ++q) { ax[q] = 0.f; ay[q] = 0.f; }

    unroll_n<32>([&](auto MC) {            // m = 0..31: lo mask halves
      constexpr int m = MC.value;
      const f32x2 wA = WsA[m * 64 + lane];
      const f32x2 wB = WsB[m * 64 + lane];
      {
        const float fE = sel_bit_valu<m>(mElo[0]);
        const float fO = sel_bit_valu<m>(mOlo[0]);
        fmac_v(ax[0], fE, wA.x); fmac_v(ay[0], fE, wA.y);
        fmac_v(ax[0], fO, wB.x); fmac_v(ay[0], fO, wB.y);
      }
      #pragma unroll
      for (int q = 1; q < R; ++q) {
        const float fE = sel_bit_salu<m>(mElo[q]);
        const float fO = sel_bit_salu<m>(mOlo[q]);
        fmac_s(ax[q], fE, wA.x); fmac_s(ay[q], fE, wA.y);
        fmac_s(ax[q], fO, wB.x); fmac_s(ay[q], fO, wB.y);
      }
    });
    unroll_n<32>([&](auto MC) {            // m = 32..63: hi mask halves
      constexpr int m = MC.value;
      const f32x2 wA = WsA[(m + 32) * 64 + lane];
      const f32x2 wB = WsB[(m + 32) * 64 + lane];
      {
        const float fE = sel_bit_valu<m>(mEhi[0]);
        const float fO = sel_bit_valu<m>(mOhi[0]);
        fmac_v(ax[0], fE, wA.x); fmac_v(ay[0], fE, wA.y);
        fmac_v(ax[0], fO, wB.x); fmac_v(ay[0], fO, wB.y);
      }
      #pragma unroll
      for (int q = 1; q < R; ++q) {
        const float fE = sel_bit_salu<m>(mEhi[q]);
        const float fO = sel_bit_salu<m>(mOhi[q]);
        fmac_s(ax[q], fE, wA.x); fmac_s(ay[q], fE, wA.y);
        fmac_s(ax[q], fO, wB.x); fmac_s(ay[q], fO, wB.y);
      }
    });

    // ---- uniforms + Bernoulli update
    const uint32_t sa = KC.sk[2 * t], sb = KC.sk[2 * t + 1];
    #pragma unroll
    for (int q = 0; q < R; ++q) {
      const uint32_t c = cb + (uint32_t)(q * LATENT) + (uint32_t)j0;
      const uint32_t uE = rbits(sa, sb, c);
      const uint32_t uO = rbits(sa, sb, c + 1u);
      const float pE = ref_sigmoid(__fadd_rn(h0, ax[q]));
      const float pO = ref_sigmoid(__fadd_rn(h1, ay[q]));
      ballot_scalar((int)(bits_to_u(uE) < pE), mElo[q], mEhi[q]);
      ballot_scalar((int)(bits_to_u(uO) < pO), mOlo[q], mOhi[q]);
    }
  }

  // ---- write z_final: R consecutive rows per wave, float2 per lane (coalesced)
  float2* out2 = reinterpret_cast<float2*>(out);
  #pragma unroll
  for (int q = 0; q < R; ++q) {
    float2 z;
    z.x = (float)(((lane < 32 ? mElo[q] : mEhi[q]) >> (lane & 31)) & 1u);
    z.y = (float)(((lane < 32 ? mOlo[q] : mOhi[q]) >> (lane & 31)) & 1u);
    out2[(size_t)(wid * R + q) * 64 + lane] = z;
  }
}

extern "C" void kernel_launch(void* const* d_in, const int* in_sizes, int n_in,
                              void* d_out, int out_size, void* d_ws, size_t ws_size,
                              hipStream_t stream) {
  const float* h = (const float*)d_in[0];
  const float* W = (const float*)d_in[1];
  float* out = (float*)d_out;
  rbm_gibbs_kernel<<<NBLOCKS, TPB, 0, stream>>>(h, W, out);
}